// Round 18
// baseline (1105.192 us; speedup 1.0000x reference)
//
#include <hip/hip_runtime.h>
#include <hip/hip_bf16.h>

typedef __hip_bfloat16 bf16;

constexpr int B  = 64, T = 120, N = 24, M = 3, D = 32;
constexpr int NH = 2, FD = 16, FF = 64, L = 3;
constexpr float SCALE = 0.25f;   // 1/sqrt(FD)
constexpr int SK  = 40;          // attnt Q/V LDS stride (bf16, 80B rows)
constexpr int SKF = 36;          // attnt K/O LDS stride (f32, 144B rows)
constexpr int CH2 = 30;          // attnt rows per chunk: 4 x 30 = 120 exactly
constexpr int RCH = 30;          // qkvt row chunks: 7680/256
constexpr int BG  = 2;           // spatial batches per block
constexpr int SR  = N * BG;      // spatial rows per block = 48
constexpr int SES = 40;          // spatial Es bf16 stride
constexpr int SQS = 32;          // spatial Q/K/V f32 stride
constexpr int FR  = 32;          // ff rows per block (8 lanes/row)

__device__ __forceinline__ float b2f(bf16 x) { return __bfloat162float(x); }
__device__ __forceinline__ float blo(unsigned u) { return __uint_as_float(u << 16); }
__device__ __forceinline__ float bhi(unsigned u) { return __uint_as_float(u & 0xffff0000u); }
__device__ __forceinline__ unsigned pk2(float a, float b) {
  bf16 x = __float2bfloat16(a), y = __float2bfloat16(b);
  unsigned short ux = *reinterpret_cast<unsigned short*>(&x);
  unsigned short uy = *reinterpret_cast<unsigned short*>(&y);
  return (unsigned)ux | ((unsigned)uy << 16);
}

// ---------------------------------------------------------------------------
// Compose q/k/v chained linears: grid = 3*U blocks.  Wc = W1@W2, bc = b1@W2+b2.
// ---------------------------------------------------------------------------
__global__ __launch_bounds__(256) void compose3_kernel(
    const float* __restrict__ W1q, const float* __restrict__ b1q,
    const float* __restrict__ W2q, const float* __restrict__ b2q,
    const float* __restrict__ W1k, const float* __restrict__ b1k,
    const float* __restrict__ W2k, const float* __restrict__ b2k,
    const float* __restrict__ W1v, const float* __restrict__ b1v,
    const float* __restrict__ W2v, const float* __restrict__ b2v,
    float* __restrict__ Wc, float* __restrict__ bc, int U) {
  int fam = blockIdx.x / U;
  int n   = blockIdx.x % U;
  const float* W1 = (fam == 0) ? W1q : (fam == 1) ? W1k : W1v;
  const float* b1 = (fam == 0) ? b1q : (fam == 1) ? b1k : b1v;
  const float* W2 = (fam == 0) ? W2q : (fam == 1) ? W2k : W2v;
  const float* b2 = (fam == 0) ? b2q : (fam == 1) ? b2k : b2v;
  const float* w1 = W1 + n * D * D;
  const float* w2 = W2 + n * D * D;
  float* wc  = Wc + (size_t)(fam * U + n) * D * D;
  float* bcp = bc + (fam * U + n) * D;
  __shared__ float s1[D * D], s2[D * D];
  for (int i = threadIdx.x; i < D * D; i += 256) { s1[i] = w1[i]; s2[i] = w2[i]; }
  __syncthreads();
  for (int i = threadIdx.x; i < D * D; i += 256) {
    int d = i >> 5, f = i & 31;
    float acc = 0.f;
#pragma unroll
    for (int e = 0; e < D; ++e) acc += s1[d * D + e] * s2[e * D + f];
    wc[i] = acc;
  }
  if (threadIdx.x < D) {
    int f = threadIdx.x;
    float acc = b2[n * D + f];
#pragma unroll
    for (int e = 0; e < D; ++e) acc += b1[n * D + e] * s2[e * D + f];
    bcp[f] = acc;
  }
}

// ---------------------------------------------------------------------------
// E[b,t,n,d] = X@E_W + E_b + pe   (bf16 out)
// ---------------------------------------------------------------------------
__global__ __launch_bounds__(256) void embed_kernel(
    const float* __restrict__ X, const float* __restrict__ pe,
    const float* __restrict__ E_W, const float* __restrict__ E_b,
    bf16* __restrict__ E) {
  int idx = blockIdx.x * 256 + threadIdx.x;
  if (idx >= B * T * N * D) return;
  int d = idx & 31;
  int n = (idx >> 5) % N;
  int bt = idx / (D * N);
  int t = bt % T;
  const float* x = X + bt * (N * M) + n * M;
  float acc = E_b[n * D + d] + pe[t * D + d];
#pragma unroll
  for (int m = 0; m < M; ++m) acc += x[m] * E_W[(n * M + m) * D + d];
  E[idx] = __float2bfloat16(acc);
}

// ---------------------------------------------------------------------------
// qkvt: composed Q/K/V projections for the temporal path.
// Weights in LDS.  Writes Qt/Kt/Vt[b][n][t][32] bf16 (t-contiguous).
// ---------------------------------------------------------------------------
__global__ __launch_bounds__(256) void qkvt_kernel(
    const bf16* __restrict__ E, const float* __restrict__ WtC,
    const float* __restrict__ btC,
    bf16* __restrict__ Qt, bf16* __restrict__ Kt, bf16* __restrict__ Vt) {
  int n     = blockIdx.x / RCH;
  int chunk = blockIdx.x % RCH;
  __shared__ float wsh[3 * D * D];
  __shared__ float bsh[3 * D];
  int tid = threadIdx.x;
  for (int i = tid; i < 3 * D * D; i += 256) {
    int fam = i >> 10, idx = i & 1023;
    wsh[i] = WtC[(size_t)(fam * N + n) * D * D + idx];
  }
  if (tid < 3 * D) {
    int fam = tid >> 5, e = tid & 31;
    bsh[tid] = btC[(fam * N + n) * D + e];
  }
  __syncthreads();

  int row = chunk * 256 + tid;          // (b*T + t)
  int b = row / T, t = row % T;
  const bf16* er = E + ((size_t)row * N + n) * D;
  float x[D];
#pragma unroll
  for (int p = 0; p < 4; ++p) {
    uint4 u = *(const uint4*)&er[p * 8];
    x[p*8+0] = blo(u.x); x[p*8+1] = bhi(u.x);
    x[p*8+2] = blo(u.y); x[p*8+3] = bhi(u.y);
    x[p*8+4] = blo(u.z); x[p*8+5] = bhi(u.z);
    x[p*8+6] = blo(u.w); x[p*8+7] = bhi(u.w);
  }
  size_t dsto = (((size_t)b * N + n) * T + t) * D;
  bf16* dsts[3] = { Qt + dsto, Kt + dsto, Vt + dsto };
#pragma unroll
  for (int fam = 0; fam < 3; ++fam) {
    const float* w  = wsh + fam * D * D;
    const float* bi = bsh + fam * D;
    bf16* dst = dsts[fam];
#pragma unroll
    for (int g = 0; g < 4; ++g) {
      float a[8];
#pragma unroll
      for (int j = 0; j < 8; ++j) a[j] = bi[g * 8 + j];
#pragma unroll
      for (int d = 0; d < D; ++d) {
        float xv = x[d];
#pragma unroll
        for (int j = 0; j < 8; ++j) a[j] += xv * w[d * D + g * 8 + j];
      }
      uint4 o;
      o.x = pk2(a[0], a[1]); o.y = pk2(a[2], a[3]);
      o.z = pk2(a[4], a[5]); o.w = pk2(a[6], a[7]);
      *(uint4*)&dst[g * 8] = o;
    }
  }
}

// ---------------------------------------------------------------------------
// attnt v8: PER-CHUNK DISPATCHES.  Template NKT = keys staged (compile-time
// LDS sizing: 18.8/25.7/32.7/38.2 KB, and sc[NJT] sizing: 8/15/23/30 regs) but
// the causal guard uses RUNTIME c — preserving v4's 68-reg codegen (R15 showed
// all-compile-time guards let the scheduler hoist loads -> 128 VGPR).
// 4 uniform dispatches/layer; c0-c2 get more blocks/CU than one-size 38.4 KB.
// ---------------------------------------------------------------------------
template<int NKT>
__global__ __launch_bounds__(256) void attnt_kernel(
    const bf16* __restrict__ Qt, const bf16* __restrict__ Kt,
    const bf16* __restrict__ Vt, const bf16* __restrict__ E,
    const float* __restrict__ tm_Wo, const float* __restrict__ tm_bo,
    const float* __restrict__ ln_g, const float* __restrict__ ln_b,
    bf16* __restrict__ Tn, int c) {
  constexpr int NKR = (NKT + 4 < T) ? NKT + 4 : T;   // staged rows incl guard
  constexpr int NJT = ((NKT - 1) >> 2) + 1;          // keys/lane: 8/15/23/30
  int bn = blockIdx.x;
  int n  = bn % N, b = bn / N;
  __shared__ __align__(16) float Kl[NKR * SKF];
  __shared__ __align__(16) bf16  Vl[NKR * SK];
  __shared__ __align__(16) bf16  Ql[CH2 * SK];
  __shared__ __align__(16) float Ol[CH2 * SKF];
  __shared__ float Wol[D * D], bol[D], gl[D], bbl[D];
  int tid = threadIdx.x;

  const bf16* Kg = Kt + (size_t)bn * T * D;
  const bf16* Vg = Vt + (size_t)bn * T * D;
  const bf16* Qg = Qt + ((size_t)bn * T + CH2 * c) * D;
  for (int i = tid; i < NKR * 4; i += 256) {
    int r = i >> 2, p = i & 3;
    if (r < NKT) {
      uint4 ku = *(const uint4*)&Kg[r * D + p * 8];
      *(float4*)&Kl[r * SKF + p * 8]     = make_float4(blo(ku.x), bhi(ku.x), blo(ku.y), bhi(ku.y));
      *(float4*)&Kl[r * SKF + p * 8 + 4] = make_float4(blo(ku.z), bhi(ku.z), blo(ku.w), bhi(ku.w));
      *(uint4*)&Vl[r * SK + p * 8]       = *(const uint4*)&Vg[r * D + p * 8];
    } else {
      *(float4*)&Kl[r * SKF + p * 8]     = make_float4(0.f, 0.f, 0.f, 0.f);
      *(float4*)&Kl[r * SKF + p * 8 + 4] = make_float4(0.f, 0.f, 0.f, 0.f);
      *(uint4*)&Vl[r * SK + p * 8]       = make_uint4(0u, 0u, 0u, 0u);
    }
  }
  if (tid < CH2 * 4) {
    int r = tid >> 2, p = tid & 3;
    *(uint4*)&Ql[r * SK + p * 8] = *(const uint4*)&Qg[r * D + p * 8];
  }
  for (int i = tid; i < D * D; i += 256) Wol[i] = tm_Wo[(size_t)n * D * D + i];
  if (tid < D) {
    bol[tid] = tm_bo[n * D + tid];
    gl[tid]  = ln_g[tid];
    bbl[tid] = ln_b[tid];
  }
  __syncthreads();

  // ---- attention: task = (row, head), 4 lanes per task ----
  {
    int task = tid >> 2, sl = tid & 3;
    if (task < 2 * CH2) {
      int rl = task >> 1, h = task & 1, ho = h * FD;
      int rg = CH2 * c + rl;                 // runtime -> v4 codegen
      uint4 q0 = *(const uint4*)&Ql[rl * SK + ho];
      uint4 q1 = *(const uint4*)&Ql[rl * SK + ho + 8];
      float qf[16];
      qf[0]  = blo(q0.x); qf[1]  = bhi(q0.x); qf[2]  = blo(q0.y); qf[3]  = bhi(q0.y);
      qf[4]  = blo(q0.z); qf[5]  = bhi(q0.z); qf[6]  = blo(q0.w); qf[7]  = bhi(q0.w);
      qf[8]  = blo(q1.x); qf[9]  = bhi(q1.x); qf[10] = blo(q1.y); qf[11] = bhi(q1.y);
      qf[12] = blo(q1.z); qf[13] = bhi(q1.z); qf[14] = blo(q1.w); qf[15] = bhi(q1.w);

      float sc[NJT];
      float mx = -3e38f;
#pragma unroll
      for (int j = 0; j < NJT; ++j) {
        int k = 4 * j + sl;
        sc[j] = -3e38f;
        if (k <= rg) {
          const float4 k0 = *(const float4*)&Kl[k * SKF + ho];
          const float4 k1 = *(const float4*)&Kl[k * SKF + ho + 4];
          const float4 k2 = *(const float4*)&Kl[k * SKF + ho + 8];
          const float4 k3 = *(const float4*)&Kl[k * SKF + ho + 12];
          float s0 = qf[0]*k0.x  + qf[1]*k0.y  + qf[2]*k0.z  + qf[3]*k0.w;
          float s1 = qf[4]*k1.x  + qf[5]*k1.y  + qf[6]*k1.z  + qf[7]*k1.w;
          float s2 = qf[8]*k2.x  + qf[9]*k2.y  + qf[10]*k2.z + qf[11]*k2.w;
          float s3 = qf[12]*k3.x + qf[13]*k3.y + qf[14]*k3.z + qf[15]*k3.w;
          float s = ((s0 + s1) + (s2 + s3)) * SCALE;
          sc[j] = s;
          mx = fmaxf(mx, s);
        }
      }
      mx = fmaxf(mx, __shfl_xor(mx, 1, 64));
      mx = fmaxf(mx, __shfl_xor(mx, 2, 64));
      float l = 0.f;
#pragma unroll
      for (int j = 0; j < NJT; ++j) {
        sc[j] = __expf(sc[j] - mx);   // invalid slots: exp(-inf) = 0
        l += sc[j];
      }
      l += __shfl_xor(l, 1, 64);
      l += __shfl_xor(l, 2, 64);
      float rli = 1.f / l;

      float acc[16];
#pragma unroll
      for (int f = 0; f < 16; ++f) acc[f] = 0.f;
#pragma unroll
      for (int j = 0; j < NJT; ++j) {
        int k = 4 * j + sl;
        if (k <= rg) {
          float p = sc[j];
          uint2 va = *(const uint2*)&Vl[k * SK + ho];
          uint2 vb = *(const uint2*)&Vl[k * SK + ho + 4];
          uint2 vc = *(const uint2*)&Vl[k * SK + ho + 8];
          uint2 vd = *(const uint2*)&Vl[k * SK + ho + 12];
          acc[0]  += p * blo(va.x); acc[1]  += p * bhi(va.x);
          acc[2]  += p * blo(va.y); acc[3]  += p * bhi(va.y);
          acc[4]  += p * blo(vb.x); acc[5]  += p * bhi(vb.x);
          acc[6]  += p * blo(vb.y); acc[7]  += p * bhi(vb.y);
          acc[8]  += p * blo(vc.x); acc[9]  += p * bhi(vc.x);
          acc[10] += p * blo(vc.y); acc[11] += p * bhi(vc.y);
          acc[12] += p * blo(vd.x); acc[13] += p * bhi(vd.x);
          acc[14] += p * blo(vd.y); acc[15] += p * bhi(vd.y);
        }
      }
#pragma unroll
      for (int f = 0; f < 16; ++f) {
        acc[f] += __shfl_xor(acc[f], 1, 64);
        acc[f] += __shfl_xor(acc[f], 2, 64);
      }
      if (sl == 0) {
#pragma unroll
        for (int f = 0; f < 16; ++f) Ol[rl * SKF + ho + f] = acc[f] * rli;
      }
    }
  }
  __syncthreads();

  // ---- O-proj + residual + LN: thread = (row, e-quad), 8 lanes per row ----
  {
    int rl = tid >> 3, q = tid & 7, e0 = q * 4;
    if (rl < CH2) {
      int rg = CH2 * c + rl;
      size_t rowo = ((size_t)(b * T + rg) * N + n) * D;
      uint2 eu = *(const uint2*)&E[rowo + e0];
      float res[4] = { blo(eu.x), bhi(eu.x), blo(eu.y), bhi(eu.y) };
      float o[4], s1 = 0.f, s2 = 0.f;
#pragma unroll
      for (int j = 0; j < 4; ++j) {
        int e = e0 + j;
        float aa = 0.f, ab = 0.f;
#pragma unroll
        for (int d = 0; d < D; d += 2) {
          aa += Ol[rl * SKF + d]     * Wol[d * D + e];
          ab += Ol[rl * SKF + d + 1] * Wol[(d + 1) * D + e];
        }
        float a = bol[e] + aa + ab + res[j];
        o[j] = a; s1 += a; s2 += a * a;
      }
      s1 += __shfl_xor(s1, 1, 64); s2 += __shfl_xor(s2, 1, 64);
      s1 += __shfl_xor(s1, 2, 64); s2 += __shfl_xor(s2, 2, 64);
      s1 += __shfl_xor(s1, 4, 64); s2 += __shfl_xor(s2, 4, 64);
      float mu  = s1 * (1.f / D);
      float var = s2 * (1.f / D) - mu * mu;
      float r = rsqrtf(var + 1e-5f);
      uint2 ou;
      ou.x = pk2((o[0]-mu)*r*gl[e0]+bbl[e0],    (o[1]-mu)*r*gl[e0+1]+bbl[e0+1]);
      ou.y = pk2((o[2]-mu)*r*gl[e0+2]+bbl[e0+2],(o[3]-mu)*r*gl[e0+3]+bbl[e0+3]);
      *(uint2*)&Tn[rowo + e0] = ou;
    }
  }
}

// ---------------------------------------------------------------------------
// spatial v2: block = (t, 2 batches), 256 threads.  Weights in LDS.
// ---------------------------------------------------------------------------
__global__ __launch_bounds__(256) void spatial_kernel(
    const bf16* __restrict__ E, const float* __restrict__ WsC,
    const float* __restrict__ bsC, const float* __restrict__ sm_Wo,
    const float* __restrict__ sm_bo, const float* __restrict__ ln_g,
    const float* __restrict__ ln_b, bf16* __restrict__ Sn) {
  int t  = blockIdx.x >> 5;          // B/BG = 32 groups per t
  int bg = blockIdx.x & 31;
  int b0 = bg * BG;
  __shared__ float Wq[D * D], Wk[D * D], Wv[D * D], Wo[D * D];
  __shared__ float bqs[D], bks[D], bvs[D], bos[D], gs[D], bbs[D];
  __shared__ __align__(16) bf16  Es[SR * SES];
  __shared__ float Qs[SR * SQS], Ks[SR * SQS], Vs[SR * SQS];
  int tid = threadIdx.x;

  for (int i = tid; i < D * D; i += 256) {
    Wq[i] = WsC[(size_t)(0 * T + t) * D * D + i];
    Wk[i] = WsC[(size_t)(1 * T + t) * D * D + i];
    Wv[i] = WsC[(size_t)(2 * T + t) * D * D + i];
    Wo[i] = sm_Wo[(size_t)t * D * D + i];
  }
  if (tid < D) {
    bqs[tid] = bsC[(0 * T + t) * D + tid];
    bks[tid] = bsC[(1 * T + t) * D + tid];
    bvs[tid] = bsC[(2 * T + t) * D + tid];
    bos[tid] = sm_bo[t * D + tid];
    gs[tid]  = ln_g[tid];
    bbs[tid] = ln_b[tid];
  }
  if (tid < SR * 4) {
    int r = tid >> 2, p = tid & 3;
    int b = b0 + r / N, n = r % N;
    *(uint4*)&Es[r * SES + p * 8] =
        *(const uint4*)&E[(((size_t)b * T + t) * N + n) * D + p * 8];
  }
  __syncthreads();

#pragma unroll 1
  for (int i = tid; i < SR * D; i += 256) {
    int r = i >> 5, e = i & 31;
    float aq = bqs[e], ak = bks[e], av = bvs[e];
#pragma unroll
    for (int d = 0; d < D; ++d) {
      float x = b2f(Es[r * SES + d]);
      aq += x * Wq[d * D + e];
      ak += x * Wk[d * D + e];
      av += x * Wv[d * D + e];
    }
    Qs[r * SQS + e] = aq;
    Ks[r * SQS + e] = ak;
    Vs[r * SQS + e] = av;
  }
  __syncthreads();

  if (tid < SR * NH) {
    int r = tid >> 1, h = tid & 1, ho = h * FD;
    int kb = (r >= N) ? N : 0;
    float q[FD];
#pragma unroll
    for (int f = 0; f < FD; ++f) q[f] = Qs[r * SQS + ho + f];
    float sc[N];
    float m = -1e30f;
#pragma unroll
    for (int k = 0; k < N; ++k) {
      float sa = 0.f, sb = 0.f;
#pragma unroll
      for (int f = 0; f < FD; f += 2) {
        sa += q[f]     * Ks[(kb + k) * SQS + ho + f];
        sb += q[f + 1] * Ks[(kb + k) * SQS + ho + f + 1];
      }
      float s = (sa + sb) * SCALE;
      sc[k] = s;
      m = fmaxf(m, s);
    }
    float l = 0.f;
#pragma unroll
    for (int k = 0; k < N; ++k) { sc[k] = __expf(sc[k] - m); l += sc[k]; }
    float rl = 1.f / l;
#pragma unroll
    for (int f = 0; f < FD; ++f) {
      float a = 0.f;
#pragma unroll
      for (int k = 0; k < N; ++k) a += sc[k] * Vs[(kb + k) * SQS + ho + f];
      Qs[r * SQS + ho + f] = a * rl;
    }
  }
  __syncthreads();

#pragma unroll 1
  for (int it = 0; it < SR * D / 256; ++it) {
    int i = it * 256 + tid;
    int r = i >> 5, e = i & 31;
    float aa = 0.f, ab = 0.f;
#pragma unroll
    for (int d = 0; d < D; d += 2) {
      aa += Qs[r * SQS + d]     * Wo[d * D + e];
      ab += Qs[r * SQS + d + 1] * Wo[(d + 1) * D + e];
    }
    float o = bos[e] + aa + ab + b2f(Es[r * SES + e]);
    float s1 = o, s2 = o * o;
    s1 += __shfl_xor(s1, 1, 64);  s2 += __shfl_xor(s2, 1, 64);
    s1 += __shfl_xor(s1, 2, 64);  s2 += __shfl_xor(s2, 2, 64);
    s1 += __shfl_xor(s1, 4, 64);  s2 += __shfl_xor(s2, 4, 64);
    s1 += __shfl_xor(s1, 8, 64);  s2 += __shfl_xor(s2, 8, 64);
    s1 += __shfl_xor(s1, 16, 64); s2 += __shfl_xor(s2, 16, 64);
    float mu  = s1 * (1.f / D);
    float var = s2 * (1.f / D) - mu * mu;
    float rr = rsqrtf(var + 1e-5f);
    int b = b0 + r / N, n = r % N;
    Sn[(((size_t)b * T + t) * N + n) * D + e] =
        __float2bfloat16((o - mu) * rr * gs[e] + bbs[e]);
  }
}

// ---------------------------------------------------------------------------
// ff v2: block = 32 rows x 8 lanes/row (grid 240).
// ---------------------------------------------------------------------------
__global__ __launch_bounds__(256) void ff_kernel(
    const bf16* __restrict__ Tn, const bf16* __restrict__ Sn,
    const float* __restrict__ W1, const float* __restrict__ b1,
    const float* __restrict__ W2, const float* __restrict__ b2,
    const float* __restrict__ ln_g, const float* __restrict__ ln_b,
    bf16* __restrict__ E) {
  __shared__ float w1s[D * FF], w2s[FF * D];
  __shared__ float bb1[FF], bb2[D], gs[D], bbs[D];
  __shared__ float tsl[FR][D + 1];
  __shared__ float hl[FR][FF + 1];
  int tid = threadIdx.x;
  int r0 = blockIdx.x * FR;
  for (int i = tid; i < D * FF; i += 256) { w1s[i] = W1[i]; w2s[i] = W2[i]; }
  if (tid < FF) bb1[tid] = b1[tid];
  if (tid < D) { bb2[tid] = b2[tid]; gs[tid] = ln_g[tid]; bbs[tid] = ln_b[tid]; }
  int r = tid >> 3, s = tid & 7;
  {
    const bf16* tp = Tn + ((size_t)(r0 + r)) * D + s * 4;
    const bf16* sp = Sn + ((size_t)(r0 + r)) * D + s * 4;
    uint2 tu = *(const uint2*)tp;
    uint2 su = *(const uint2*)sp;
    tsl[r][s*4+0] = blo(tu.x) + blo(su.x);
    tsl[r][s*4+1] = bhi(tu.x) + bhi(su.x);
    tsl[r][s*4+2] = blo(tu.y) + blo(su.y);
    tsl[r][s*4+3] = bhi(tu.y) + bhi(su.y);
  }
  __syncthreads();
  {
    float hh[8];
#pragma unroll
    for (int j = 0; j < 8; ++j) {
      int jj = s * 8 + j;
      float aa = bb1[jj], ab = 0.f;
#pragma unroll
      for (int d = 0; d < D; d += 2) {
        aa += tsl[r][d]     * w1s[d * FF + jj];
        ab += tsl[r][d + 1] * w1s[(d + 1) * FF + jj];
      }
      hh[j] = fmaxf(aa + ab, 0.f);
    }
#pragma unroll
    for (int j = 0; j < 8; ++j) hl[r][s * 8 + j] = hh[j];
  }
  __syncthreads();
  {
    float x[4];
    float s1 = 0.f, s2 = 0.f;
#pragma unroll
    for (int j4 = 0; j4 < 4; ++j4) {
      int e = s * 4 + j4;
      float aa = 0.f, ab = 0.f;
#pragma unroll
      for (int k = 0; k < FF; k += 2) {
        aa += hl[r][k]     * w2s[k * D + e];
        ab += hl[r][k + 1] * w2s[(k + 1) * D + e];
      }
      float a = bb2[e] + tsl[r][e] + aa + ab;
      x[j4] = a; s1 += a; s2 += a * a;
    }
    s1 += __shfl_xor(s1, 1, 64); s2 += __shfl_xor(s2, 1, 64);
    s1 += __shfl_xor(s1, 2, 64); s2 += __shfl_xor(s2, 2, 64);
    s1 += __shfl_xor(s1, 4, 64); s2 += __shfl_xor(s2, 4, 64);
    float mu  = s1 * (1.f / D);
    float var = s2 * (1.f / D) - mu * mu;
    float rr = rsqrtf(var + 1e-5f);
    int e0 = s * 4;
    uint2 ou;
    ou.x = pk2((x[0]-mu)*rr*gs[e0]+bbs[e0],    (x[1]-mu)*rr*gs[e0+1]+bbs[e0+1]);
    ou.y = pk2((x[2]-mu)*rr*gs[e0+2]+bbs[e0+2],(x[3]-mu)*rr*gs[e0+3]+bbs[e0+3]);
    *(uint2*)&E[((size_t)(r0 + r)) * D + e0] = ou;
  }
}

// ---------------------------------------------------------------------------
// out = E@op_W + op_b + X   (f32 out)
// ---------------------------------------------------------------------------
__global__ __launch_bounds__(256) void out_kernel(
    const bf16* __restrict__ E, const float* __restrict__ op_W,
    const float* __restrict__ op_b, const float* __restrict__ X,
    float* __restrict__ out) {
  int idx = blockIdx.x * 256 + threadIdx.x;
  if (idx >= B * T * N * M) return;
  int m  = idx % M;
  int n  = (idx / M) % N;
  int bt = idx / (M * N);
  float acc = op_b[n * M + m];
  const bf16* e = E + ((size_t)bt * N + n) * D;
#pragma unroll
  for (int d = 0; d < D; ++d) acc += b2f(e[d]) * op_W[(n * D + d) * M + m];
  acc += X[idx];
  out[idx] = acc;
}

// ---------------------------------------------------------------------------
extern "C" void kernel_launch(void* const* d_in, const int* in_sizes, int n_in,
                              void* d_out, int out_size, void* d_ws, size_t ws_size,
                              hipStream_t stream) {
  const float* X     = (const float*)d_in[0];
  const float* pe    = (const float*)d_in[1];
  const float* E_W   = (const float*)d_in[2];
  const float* E_b   = (const float*)d_in[3];
  const float* tq_W  = (const float*)d_in[4];
  const float* tq_b  = (const float*)d_in[5];
  const float* tk_W  = (const float*)d_in[6];
  const float* tk_b  = (const float*)d_in[7];
  const float* tv_W  = (const float*)d_in[8];
  const float* tv_b  = (const float*)d_in[9];
  const float* tm_Wq = (const float*)d_in[10];
  const float* tm_bq = (const float*)d_in[11];
  const float* tm_Wk = (const float*)d_in[12];
  const float* tm_bk = (const float*)d_in[13];
  const float* tm_Wv = (const float*)d_in[14];
  const float* tm_bv = (const float*)d_in[15];
  const float* tm_Wo = (const float*)d_in[16];
  const float* tm_bo = (const float*)d_in[17];
  const float* sq_W  = (const float*)d_in[18];
  const float* sq_b  = (const float*)d_in[19];
  const float* sk_W  = (const float*)d_in[20];
  const float* sk_b  = (const float*)d_in[21];
  const float* sv_W  = (const float*)d_in[22];
  const float* sv_b  = (const float*)d_in[23];
  const float* sm_Wq = (const float*)d_in[24];
  const float* sm_bq = (const float*)d_in[25];
  const float* sm_Wk = (const float*)d_in[26];
  const float* sm_bk = (const float*)d_in[27];
  const float* sm_Wv = (const float*)d_in[28];
  const float* sm_bv = (const float*)d_in[29];
  const float* sm_Wo = (const float*)d_in[30];
  const float* sm_bo = (const float*)d_in[31];
  const float* ff1_W = (const float*)d_in[32];
  const float* ff1_b = (const float*)d_in[33];
  const float* ff2_W = (const float*)d_in[34];
  const float* ff2_b = (const float*)d_in[35];
  const float* ln_g  = (const float*)d_in[36];
  const float* ln_b  = (const float*)d_in[37];
  const float* op_W  = (const float*)d_in[38];
  const float* op_b  = (const float*)d_in[39];
  float* out = (float*)d_out;

  float* WtC = (float*)d_ws;                         // 3*N*D*D
  float* btC = WtC + 3 * N * D * D;                  // 3*N*D
  float* WsC = btC + 3 * N * D;                      // 3*T*D*D
  float* bsC = WsC + 3 * T * D * D;                  // 3*T*D
  size_t act = (size_t)B * T * N * D;
  bf16* Ebuf = (bf16*)(bsC + 3 * T * D);
  bf16* Tn   = Ebuf + act;
  bf16* Qt   = Tn + act;
  bf16* Kt   = Qt + act;
  bf16* Vt   = Kt + act;
  bf16* Sn   = Qt;                                   // alias

  compose3_kernel<<<3 * N, 256, 0, stream>>>(
      tq_W, tq_b, tm_Wq, tm_bq, tk_W, tk_b, tm_Wk, tm_bk,
      tv_W, tv_b, tm_Wv, tm_bv, WtC, btC, N);
  compose3_kernel<<<3 * T, 256, 0, stream>>>(
      sq_W, sq_b, sm_Wq, sm_bq, sk_W, sk_b, sm_Wk, sm_bk,
      sv_W, sv_b, sm_Wv, sm_bv, WsC, bsC, T);

  embed_kernel<<<(B * T * N * D) / 256, 256, 0, stream>>>(X, pe, E_W, E_b, Ebuf);

  for (int l = 0; l < L; ++l) {
    qkvt_kernel<<<N * RCH, 256, 0, stream>>>(Ebuf, WtC, btC, Qt, Kt, Vt);
    attnt_kernel<30><<<B * N, 256, 0, stream>>>(Qt, Kt, Vt, Ebuf, tm_Wo, tm_bo, ln_g, ln_b, Tn, 0);
    attnt_kernel<60><<<B * N, 256, 0, stream>>>(Qt, Kt, Vt, Ebuf, tm_Wo, tm_bo, ln_g, ln_b, Tn, 1);
    attnt_kernel<90><<<B * N, 256, 0, stream>>>(Qt, Kt, Vt, Ebuf, tm_Wo, tm_bo, ln_g, ln_b, Tn, 2);
    attnt_kernel<120><<<B * N, 256, 0, stream>>>(Qt, Kt, Vt, Ebuf, tm_Wo, tm_bo, ln_g, ln_b, Tn, 3);
    spatial_kernel<<<T * (B / BG), 256, 0, stream>>>(Ebuf, WsC, bsC, sm_Wo, sm_bo, ln_g, ln_b, Sn);
    ff_kernel<<<(B * T * N) / FR, 256, 0, stream>>>(Tn, Sn, ff1_W, ff1_b, ff2_W, ff2_b, ln_g, ln_b, Ebuf);
  }

  out_kernel<<<(B * T * N * M + 255) / 256, 256, 0, stream>>>(Ebuf, op_W, op_b, X, out);
}

// Round 19
// 825.781 us; speedup vs baseline: 1.3384x; 1.3384x over previous
//
#include <hip/hip_runtime.h>
#include <hip/hip_bf16.h>

typedef __hip_bfloat16 bf16;

constexpr int B  = 64, T = 120, N = 24, M = 3, D = 32;
constexpr int NH = 2, FD = 16, FF = 64, L = 3;
constexpr float SCALE = 0.25f;   // 1/sqrt(FD)
constexpr int SK  = 40;          // attnt Q/V LDS stride (bf16, 80B rows)
constexpr int SKF = 36;          // attnt K/O LDS stride (f32, 144B rows)
constexpr int CH2 = 30;          // attnt rows per chunk: 4 x 30 = 120 exactly
constexpr int NJ  = 30;          // max keys per lane slice (120/4)
constexpr int QR  = 64;          // qkvt rows per block (4 lanes/row)
constexpr int QCH = (B * T) / QR;// qkvt chunks = 120
constexpr int BG  = 2;           // spatial batches per block
constexpr int SR  = N * BG;      // spatial rows per block = 48
constexpr int SES = 40;          // Es bf16 stride (80B)
constexpr int SQS = 33;          // spatial Q/K/V f32 stride (33 -> no 32-way conflicts)
constexpr int FR  = 32;          // ff rows per block (8 lanes/row)

__device__ __forceinline__ float b2f(bf16 x) { return __bfloat162float(x); }
__device__ __forceinline__ float blo(unsigned u) { return __uint_as_float(u << 16); }
__device__ __forceinline__ float bhi(unsigned u) { return __uint_as_float(u & 0xffff0000u); }
__device__ __forceinline__ unsigned pk2(float a, float b) {
  bf16 x = __float2bfloat16(a), y = __float2bfloat16(b);
  unsigned short ux = *reinterpret_cast<unsigned short*>(&x);
  unsigned short uy = *reinterpret_cast<unsigned short*>(&y);
  return (unsigned)ux | ((unsigned)uy << 16);
}

// ---------------------------------------------------------------------------
// Compose q/k/v chained linears: grid = 3*U blocks.  Wc = W1@W2, bc = b1@W2+b2.
// ---------------------------------------------------------------------------
__global__ __launch_bounds__(256) void compose3_kernel(
    const float* __restrict__ W1q, const float* __restrict__ b1q,
    const float* __restrict__ W2q, const float* __restrict__ b2q,
    const float* __restrict__ W1k, const float* __restrict__ b1k,
    const float* __restrict__ W2k, const float* __restrict__ b2k,
    const float* __restrict__ W1v, const float* __restrict__ b1v,
    const float* __restrict__ W2v, const float* __restrict__ b2v,
    float* __restrict__ Wc, float* __restrict__ bc, int U) {
  int fam = blockIdx.x / U;
  int n   = blockIdx.x % U;
  const float* W1 = (fam == 0) ? W1q : (fam == 1) ? W1k : W1v;
  const float* b1 = (fam == 0) ? b1q : (fam == 1) ? b1k : b1v;
  const float* W2 = (fam == 0) ? W2q : (fam == 1) ? W2k : W2v;
  const float* b2 = (fam == 0) ? b2q : (fam == 1) ? b2k : b2v;
  const float* w1 = W1 + n * D * D;
  const float* w2 = W2 + n * D * D;
  float* wc  = Wc + (size_t)(fam * U + n) * D * D;
  float* bcp = bc + (fam * U + n) * D;
  __shared__ float s1[D * D], s2[D * D];
  for (int i = threadIdx.x; i < D * D; i += 256) { s1[i] = w1[i]; s2[i] = w2[i]; }
  __syncthreads();
  for (int i = threadIdx.x; i < D * D; i += 256) {
    int d = i >> 5, f = i & 31;
    float acc = 0.f;
#pragma unroll
    for (int e = 0; e < D; ++e) acc += s1[d * D + e] * s2[e * D + f];
    wc[i] = acc;
  }
  if (threadIdx.x < D) {
    int f = threadIdx.x;
    float acc = b2[n * D + f];
#pragma unroll
    for (int e = 0; e < D; ++e) acc += b1[n * D + e] * s2[e * D + f];
    bcp[f] = acc;
  }
}

// ---------------------------------------------------------------------------
// E[b,t,n,d] = X@E_W + E_b + pe   (bf16 out)
// ---------------------------------------------------------------------------
__global__ __launch_bounds__(256) void embed_kernel(
    const float* __restrict__ X, const float* __restrict__ pe,
    const float* __restrict__ E_W, const float* __restrict__ E_b,
    bf16* __restrict__ E) {
  int idx = blockIdx.x * 256 + threadIdx.x;
  if (idx >= B * T * N * D) return;
  int d = idx & 31;
  int n = (idx >> 5) % N;
  int bt = idx / (D * N);
  int t = bt % T;
  const float* x = X + bt * (N * M) + n * M;
  float acc = E_b[n * D + d] + pe[t * D + d];
#pragma unroll
  for (int m = 0; m < M; ++m) acc += x[m] * E_W[(n * M + m) * D + d];
  E[idx] = __float2bfloat16(acc);
}

// ---------------------------------------------------------------------------
// qkvt v2: thread = (row, quarter).  R18 showed v1 latency-bound (VALU 14%,
// FETCH 13/7.4MB, WRITE 38/11MB): lane-strided 16B accesses at 1536B row
// stride.  v2 stages 64 rows via fully-coalesced 64B/row loads into LDS,
// each thread computes 8 outputs/family, stores ONE contiguous uint4/family.
// Grid n-major (24 x 120) so same-n blocks share weights in L2.
// ---------------------------------------------------------------------------
__global__ __launch_bounds__(256) void qkvt_kernel(
    const bf16* __restrict__ E, const float* __restrict__ WtC,
    const float* __restrict__ btC,
    bf16* __restrict__ Qt, bf16* __restrict__ Kt, bf16* __restrict__ Vt) {
  int n     = blockIdx.x / QCH;
  int chunk = blockIdx.x % QCH;
  __shared__ float wsh[3 * D * D];
  __shared__ float bsh[3 * D];
  __shared__ __align__(16) bf16 Es[QR * SES];
  int tid = threadIdx.x;
  for (int i = tid; i < 3 * D * D; i += 256) {
    int fam = i >> 10, idx = i & 1023;
    wsh[i] = WtC[(size_t)(fam * N + n) * D * D + idx];
  }
  if (tid < 3 * D) {
    int fam = tid >> 5, e = tid & 31;
    bsh[tid] = btC[(fam * N + n) * D + e];
  }
  {
    int row = tid >> 2, p = tid & 3;
    const bf16* er = E + ((size_t)(chunk * QR + row) * N + n) * D;
    *(uint4*)&Es[row * SES + p * 8] = *(const uint4*)&er[p * 8];
  }
  __syncthreads();

  int row = tid >> 2, q = tid & 3;
  int grow = chunk * QR + row;          // b*T + t
  int b = grow / T, t = grow % T;
  float x[D];
#pragma unroll
  for (int d = 0; d < D; ++d) x[d] = b2f(Es[row * SES + d]);
  size_t dsto = (((size_t)b * N + n) * T + t) * D + q * 8;
  bf16* dsts[3] = { Qt + dsto, Kt + dsto, Vt + dsto };
#pragma unroll
  for (int fam = 0; fam < 3; ++fam) {
    const float* w  = wsh + fam * D * D;
    const float* bi = bsh + fam * D;
    float a[8];
#pragma unroll
    for (int j = 0; j < 8; ++j) a[j] = bi[q * 8 + j];
#pragma unroll
    for (int d = 0; d < D; ++d) {
      float xv = x[d];
#pragma unroll
      for (int j = 0; j < 8; ++j) a[j] += xv * w[d * D + q * 8 + j];
    }
    uint4 o;
    o.x = pk2(a[0], a[1]); o.y = pk2(a[2], a[3]);
    o.z = pk2(a[4], a[5]); o.w = pk2(a[6], a[7]);
    *(uint4*)dsts[fam] = o;
  }
}

// ---------------------------------------------------------------------------
// attnt v4 (R17 single-dispatch — measured best: 68 VGPR, 25% occ, 134us).
// R18's per-chunk 4-dispatch split serialized and cost ~36us net; reverted.
// ---------------------------------------------------------------------------
__global__ __launch_bounds__(256) void attnt_kernel(
    const bf16* __restrict__ Qt, const bf16* __restrict__ Kt,
    const bf16* __restrict__ Vt, const bf16* __restrict__ E,
    const float* __restrict__ tm_Wo, const float* __restrict__ tm_bo,
    const float* __restrict__ ln_g, const float* __restrict__ ln_b,
    bf16* __restrict__ Tn) {
  int c  = blockIdx.x & 3;
  int bn = blockIdx.x >> 2;
  int n  = bn % N, b = bn / N;
  int nk = CH2 * (c + 1);               // keys staged: 30/60/90/120
  __shared__ __align__(16) float Kl[T * SKF];
  __shared__ __align__(16) bf16  Vl[T * SK];
  __shared__ __align__(16) bf16  Ql[CH2 * SK];
  __shared__ __align__(16) float Ol[CH2 * SKF];
  __shared__ float Wol[D * D], bol[D], gl[D], bbl[D];
  int tid = threadIdx.x;

  const bf16* Kg = Kt + (size_t)bn * T * D;
  const bf16* Vg = Vt + (size_t)bn * T * D;
  const bf16* Qg = Qt + ((size_t)bn * T + CH2 * c) * D;
  for (int i = tid; i < T * 4; i += 256) {
    int r = i >> 2, p = i & 3;
    if (r < nk) {
      uint4 ku = *(const uint4*)&Kg[r * D + p * 8];
      *(float4*)&Kl[r * SKF + p * 8]     = make_float4(blo(ku.x), bhi(ku.x), blo(ku.y), bhi(ku.y));
      *(float4*)&Kl[r * SKF + p * 8 + 4] = make_float4(blo(ku.z), bhi(ku.z), blo(ku.w), bhi(ku.w));
      *(uint4*)&Vl[r * SK + p * 8]       = *(const uint4*)&Vg[r * D + p * 8];
    } else {
      *(float4*)&Kl[r * SKF + p * 8]     = make_float4(0.f, 0.f, 0.f, 0.f);
      *(float4*)&Kl[r * SKF + p * 8 + 4] = make_float4(0.f, 0.f, 0.f, 0.f);
      *(uint4*)&Vl[r * SK + p * 8]       = make_uint4(0u, 0u, 0u, 0u);
    }
  }
  if (tid < CH2 * 4) {
    int r = tid >> 2, p = tid & 3;
    *(uint4*)&Ql[r * SK + p * 8] = *(const uint4*)&Qg[r * D + p * 8];
  }
  for (int i = tid; i < D * D; i += 256) Wol[i] = tm_Wo[(size_t)n * D * D + i];
  if (tid < D) {
    bol[tid] = tm_bo[n * D + tid];
    gl[tid]  = ln_g[tid];
    bbl[tid] = ln_b[tid];
  }
  __syncthreads();

  // ---- attention: task = (row, head), 4 lanes per task ----
  {
    int task = tid >> 2, sl = tid & 3;
    if (task < 2 * CH2) {
      int rl = task >> 1, h = task & 1, ho = h * FD;
      int rg = CH2 * c + rl;
      uint4 q0 = *(const uint4*)&Ql[rl * SK + ho];
      uint4 q1 = *(const uint4*)&Ql[rl * SK + ho + 8];
      float qf[16];
      qf[0]  = blo(q0.x); qf[1]  = bhi(q0.x); qf[2]  = blo(q0.y); qf[3]  = bhi(q0.y);
      qf[4]  = blo(q0.z); qf[5]  = bhi(q0.z); qf[6]  = blo(q0.w); qf[7]  = bhi(q0.w);
      qf[8]  = blo(q1.x); qf[9]  = bhi(q1.x); qf[10] = blo(q1.y); qf[11] = bhi(q1.y);
      qf[12] = blo(q1.z); qf[13] = bhi(q1.z); qf[14] = blo(q1.w); qf[15] = bhi(q1.w);

      float sc[NJ];
      float mx = -3e38f;
#pragma unroll
      for (int j = 0; j < NJ; ++j) {
        int k = 4 * j + sl;
        sc[j] = -3e38f;
        if (k <= rg) {
          const float4 k0 = *(const float4*)&Kl[k * SKF + ho];
          const float4 k1 = *(const float4*)&Kl[k * SKF + ho + 4];
          const float4 k2 = *(const float4*)&Kl[k * SKF + ho + 8];
          const float4 k3 = *(const float4*)&Kl[k * SKF + ho + 12];
          float s0 = qf[0]*k0.x  + qf[1]*k0.y  + qf[2]*k0.z  + qf[3]*k0.w;
          float s1 = qf[4]*k1.x  + qf[5]*k1.y  + qf[6]*k1.z  + qf[7]*k1.w;
          float s2 = qf[8]*k2.x  + qf[9]*k2.y  + qf[10]*k2.z + qf[11]*k2.w;
          float s3 = qf[12]*k3.x + qf[13]*k3.y + qf[14]*k3.z + qf[15]*k3.w;
          float s = ((s0 + s1) + (s2 + s3)) * SCALE;
          sc[j] = s;
          mx = fmaxf(mx, s);
        }
      }
      mx = fmaxf(mx, __shfl_xor(mx, 1, 64));
      mx = fmaxf(mx, __shfl_xor(mx, 2, 64));
      float l = 0.f;
#pragma unroll
      for (int j = 0; j < NJ; ++j) {
        sc[j] = __expf(sc[j] - mx);   // invalid slots: exp(-inf) = 0
        l += sc[j];
      }
      l += __shfl_xor(l, 1, 64);
      l += __shfl_xor(l, 2, 64);
      float rli = 1.f / l;

      float acc[16];
#pragma unroll
      for (int f = 0; f < 16; ++f) acc[f] = 0.f;
#pragma unroll
      for (int j = 0; j < NJ; ++j) {
        int k = 4 * j + sl;
        if (k <= rg) {
          float p = sc[j];
          uint2 va = *(const uint2*)&Vl[k * SK + ho];
          uint2 vb = *(const uint2*)&Vl[k * SK + ho + 4];
          uint2 vc = *(const uint2*)&Vl[k * SK + ho + 8];
          uint2 vd = *(const uint2*)&Vl[k * SK + ho + 12];
          acc[0]  += p * blo(va.x); acc[1]  += p * bhi(va.x);
          acc[2]  += p * blo(va.y); acc[3]  += p * bhi(va.y);
          acc[4]  += p * blo(vb.x); acc[5]  += p * bhi(vb.x);
          acc[6]  += p * blo(vb.y); acc[7]  += p * bhi(vb.y);
          acc[8]  += p * blo(vc.x); acc[9]  += p * bhi(vc.x);
          acc[10] += p * blo(vc.y); acc[11] += p * bhi(vc.y);
          acc[12] += p * blo(vd.x); acc[13] += p * bhi(vd.x);
          acc[14] += p * blo(vd.y); acc[15] += p * bhi(vd.y);
        }
      }
#pragma unroll
      for (int f = 0; f < 16; ++f) {
        acc[f] += __shfl_xor(acc[f], 1, 64);
        acc[f] += __shfl_xor(acc[f], 2, 64);
      }
      if (sl == 0) {
#pragma unroll
        for (int f = 0; f < 16; ++f) Ol[rl * SKF + ho + f] = acc[f] * rli;
      }
    }
  }
  __syncthreads();

  // ---- O-proj + residual + LN: thread = (row, e-quad), 8 lanes per row ----
  {
    int rl = tid >> 3, q = tid & 7, e0 = q * 4;
    if (rl < CH2) {
      int rg = CH2 * c + rl;
      size_t rowo = ((size_t)(b * T + rg) * N + n) * D;
      uint2 eu = *(const uint2*)&E[rowo + e0];
      float res[4] = { blo(eu.x), bhi(eu.x), blo(eu.y), bhi(eu.y) };
      float o[4], s1 = 0.f, s2 = 0.f;
#pragma unroll
      for (int j = 0; j < 4; ++j) {
        int e = e0 + j;
        float aa = 0.f, ab = 0.f;
#pragma unroll
        for (int d = 0; d < D; d += 2) {
          aa += Ol[rl * SKF + d]     * Wol[d * D + e];
          ab += Ol[rl * SKF + d + 1] * Wol[(d + 1) * D + e];
        }
        float a = bol[e] + aa + ab + res[j];
        o[j] = a; s1 += a; s2 += a * a;
      }
      s1 += __shfl_xor(s1, 1, 64); s2 += __shfl_xor(s2, 1, 64);
      s1 += __shfl_xor(s1, 2, 64); s2 += __shfl_xor(s2, 2, 64);
      s1 += __shfl_xor(s1, 4, 64); s2 += __shfl_xor(s2, 4, 64);
      float mu  = s1 * (1.f / D);
      float var = s2 * (1.f / D) - mu * mu;
      float r = rsqrtf(var + 1e-5f);
      uint2 ou;
      ou.x = pk2((o[0]-mu)*r*gl[e0]+bbl[e0],    (o[1]-mu)*r*gl[e0+1]+bbl[e0+1]);
      ou.y = pk2((o[2]-mu)*r*gl[e0+2]+bbl[e0+2],(o[3]-mu)*r*gl[e0+3]+bbl[e0+3]);
      *(uint2*)&Tn[rowo + e0] = ou;
    }
  }
}

// ---------------------------------------------------------------------------
// spatial v3: SQS 32 -> 33.  R18 PMC showed 2.4M LDS bank conflicts: stride-32
// f32 rows put every row on bank 0, so same-h lanes reading 32 distinct K/V
// rows at fixed f hit ONE bank 32-wide.  Stride 33 spreads rows across banks.
// ---------------------------------------------------------------------------
__global__ __launch_bounds__(256) void spatial_kernel(
    const bf16* __restrict__ E, const float* __restrict__ WsC,
    const float* __restrict__ bsC, const float* __restrict__ sm_Wo,
    const float* __restrict__ sm_bo, const float* __restrict__ ln_g,
    const float* __restrict__ ln_b, bf16* __restrict__ Sn) {
  int t  = blockIdx.x >> 5;          // B/BG = 32 groups per t
  int bg = blockIdx.x & 31;
  int b0 = bg * BG;
  __shared__ float Wq[D * D], Wk[D * D], Wv[D * D], Wo[D * D];
  __shared__ float bqs[D], bks[D], bvs[D], bos[D], gs[D], bbs[D];
  __shared__ __align__(16) bf16  Es[SR * SES];
  __shared__ float Qs[SR * SQS], Ks[SR * SQS], Vs[SR * SQS];
  int tid = threadIdx.x;

  for (int i = tid; i < D * D; i += 256) {
    Wq[i] = WsC[(size_t)(0 * T + t) * D * D + i];
    Wk[i] = WsC[(size_t)(1 * T + t) * D * D + i];
    Wv[i] = WsC[(size_t)(2 * T + t) * D * D + i];
    Wo[i] = sm_Wo[(size_t)t * D * D + i];
  }
  if (tid < D) {
    bqs[tid] = bsC[(0 * T + t) * D + tid];
    bks[tid] = bsC[(1 * T + t) * D + tid];
    bvs[tid] = bsC[(2 * T + t) * D + tid];
    bos[tid] = sm_bo[t * D + tid];
    gs[tid]  = ln_g[tid];
    bbs[tid] = ln_b[tid];
  }
  if (tid < SR * 4) {
    int r = tid >> 2, p = tid & 3;
    int b = b0 + r / N, n = r % N;
    *(uint4*)&Es[r * SES + p * 8] =
        *(const uint4*)&E[(((size_t)b * T + t) * N + n) * D + p * 8];
  }
  __syncthreads();

#pragma unroll 1
  for (int i = tid; i < SR * D; i += 256) {
    int r = i >> 5, e = i & 31;
    float aq = bqs[e], ak = bks[e], av = bvs[e];
#pragma unroll
    for (int d = 0; d < D; ++d) {
      float x = b2f(Es[r * SES + d]);
      aq += x * Wq[d * D + e];
      ak += x * Wk[d * D + e];
      av += x * Wv[d * D + e];
    }
    Qs[r * SQS + e] = aq;
    Ks[r * SQS + e] = ak;
    Vs[r * SQS + e] = av;
  }
  __syncthreads();

  if (tid < SR * NH) {
    int r = tid >> 1, h = tid & 1, ho = h * FD;
    int kb = (r >= N) ? N : 0;
    float q[FD];
#pragma unroll
    for (int f = 0; f < FD; ++f) q[f] = Qs[r * SQS + ho + f];
    float sc[N];
    float m = -1e30f;
#pragma unroll
    for (int k = 0; k < N; ++k) {
      float sa = 0.f, sb = 0.f;
#pragma unroll
      for (int f = 0; f < FD; f += 2) {
        sa += q[f]     * Ks[(kb + k) * SQS + ho + f];
        sb += q[f + 1] * Ks[(kb + k) * SQS + ho + f + 1];
      }
      float s = (sa + sb) * SCALE;
      sc[k] = s;
      m = fmaxf(m, s);
    }
    float l = 0.f;
#pragma unroll
    for (int k = 0; k < N; ++k) { sc[k] = __expf(sc[k] - m); l += sc[k]; }
    float rl = 1.f / l;
#pragma unroll
    for (int f = 0; f < FD; ++f) {
      float a = 0.f;
#pragma unroll
      for (int k = 0; k < N; ++k) a += sc[k] * Vs[(kb + k) * SQS + ho + f];
      Qs[r * SQS + ho + f] = a * rl;
    }
  }
  __syncthreads();

#pragma unroll 1
  for (int it = 0; it < SR * D / 256; ++it) {
    int i = it * 256 + tid;
    int r = i >> 5, e = i & 31;
    float aa = 0.f, ab = 0.f;
#pragma unroll
    for (int d = 0; d < D; d += 2) {
      aa += Qs[r * SQS + d]     * Wo[d * D + e];
      ab += Qs[r * SQS + d + 1] * Wo[(d + 1) * D + e];
    }
    float o = bos[e] + aa + ab + b2f(Es[r * SES + e]);
    float s1 = o, s2 = o * o;
    s1 += __shfl_xor(s1, 1, 64);  s2 += __shfl_xor(s2, 1, 64);
    s1 += __shfl_xor(s1, 2, 64);  s2 += __shfl_xor(s2, 2, 64);
    s1 += __shfl_xor(s1, 4, 64);  s2 += __shfl_xor(s2, 4, 64);
    s1 += __shfl_xor(s1, 8, 64);  s2 += __shfl_xor(s2, 8, 64);
    s1 += __shfl_xor(s1, 16, 64); s2 += __shfl_xor(s2, 16, 64);
    float mu  = s1 * (1.f / D);
    float var = s2 * (1.f / D) - mu * mu;
    float rr = rsqrtf(var + 1e-5f);
    int b = b0 + r / N, n = r % N;
    Sn[(((size_t)b * T + t) * N + n) * D + e] =
        __float2bfloat16((o - mu) * rr * gs[e] + bbs[e]);
  }
}

// ---------------------------------------------------------------------------
// ff v2: block = 32 rows x 8 lanes/row (grid 240).
// ---------------------------------------------------------------------------
__global__ __launch_bounds__(256) void ff_kernel(
    const bf16* __restrict__ Tn, const bf16* __restrict__ Sn,
    const float* __restrict__ W1, const float* __restrict__ b1,
    const float* __restrict__ W2, const float* __restrict__ b2,
    const float* __restrict__ ln_g, const float* __restrict__ ln_b,
    bf16* __restrict__ E) {
  __shared__ float w1s[D * FF], w2s[FF * D];
  __shared__ float bb1[FF], bb2[D], gs[D], bbs[D];
  __shared__ float tsl[FR][D + 1];
  __shared__ float hl[FR][FF + 1];
  int tid = threadIdx.x;
  int r0 = blockIdx.x * FR;
  for (int i = tid; i < D * FF; i += 256) { w1s[i] = W1[i]; w2s[i] = W2[i]; }
  if (tid < FF) bb1[tid] = b1[tid];
  if (tid < D) { bb2[tid] = b2[tid]; gs[tid] = ln_g[tid]; bbs[tid] = ln_b[tid]; }
  int r = tid >> 3, s = tid & 7;
  {
    const bf16* tp = Tn + ((size_t)(r0 + r)) * D + s * 4;
    const bf16* sp = Sn + ((size_t)(r0 + r)) * D + s * 4;
    uint2 tu = *(const uint2*)tp;
    uint2 su = *(const uint2*)sp;
    tsl[r][s*4+0] = blo(tu.x) + blo(su.x);
    tsl[r][s*4+1] = bhi(tu.x) + bhi(su.x);
    tsl[r][s*4+2] = blo(tu.y) + blo(su.y);
    tsl[r][s*4+3] = bhi(tu.y) + bhi(su.y);
  }
  __syncthreads();
  {
    float hh[8];
#pragma unroll
    for (int j = 0; j < 8; ++j) {
      int jj = s * 8 + j;
      float aa = bb1[jj], ab = 0.f;
#pragma unroll
      for (int d = 0; d < D; d += 2) {
        aa += tsl[r][d]     * w1s[d * FF + jj];
        ab += tsl[r][d + 1] * w1s[(d + 1) * FF + jj];
      }
      hh[j] = fmaxf(aa + ab, 0.f);
    }
#pragma unroll
    for (int j = 0; j < 8; ++j) hl[r][s * 8 + j] = hh[j];
  }
  __syncthreads();
  {
    float x[4];
    float s1 = 0.f, s2 = 0.f;
#pragma unroll
    for (int j4 = 0; j4 < 4; ++j4) {
      int e = s * 4 + j4;
      float aa = 0.f, ab = 0.f;
#pragma unroll
      for (int k = 0; k < FF; k += 2) {
        aa += hl[r][k]     * w2s[k * D + e];
        ab += hl[r][k + 1] * w2s[(k + 1) * D + e];
      }
      float a = bb2[e] + tsl[r][e] + aa + ab;
      x[j4] = a; s1 += a; s2 += a * a;
    }
    s1 += __shfl_xor(s1, 1, 64); s2 += __shfl_xor(s2, 1, 64);
    s1 += __shfl_xor(s1, 2, 64); s2 += __shfl_xor(s2, 2, 64);
    s1 += __shfl_xor(s1, 4, 64); s2 += __shfl_xor(s2, 4, 64);
    float mu  = s1 * (1.f / D);
    float var = s2 * (1.f / D) - mu * mu;
    float rr = rsqrtf(var + 1e-5f);
    int e0 = s * 4;
    uint2 ou;
    ou.x = pk2((x[0]-mu)*rr*gs[e0]+bbs[e0],    (x[1]-mu)*rr*gs[e0+1]+bbs[e0+1]);
    ou.y = pk2((x[2]-mu)*rr*gs[e0+2]+bbs[e0+2],(x[3]-mu)*rr*gs[e0+3]+bbs[e0+3]);
    *(uint2*)&E[((size_t)(r0 + r)) * D + e0] = ou;
  }
}

// ---------------------------------------------------------------------------
// out = E@op_W + op_b + X   (f32 out)
// ---------------------------------------------------------------------------
__global__ __launch_bounds__(256) void out_kernel(
    const bf16* __restrict__ E, const float* __restrict__ op_W,
    const float* __restrict__ op_b, const float* __restrict__ X,
    float* __restrict__ out) {
  int idx = blockIdx.x * 256 + threadIdx.x;
  if (idx >= B * T * N * M) return;
  int m  = idx % M;
  int n  = (idx / M) % N;
  int bt = idx / (M * N);
  float acc = op_b[n * M + m];
  const bf16* e = E + ((size_t)bt * N + n) * D;
#pragma unroll
  for (int d = 0; d < D; ++d) acc += b2f(e[d]) * op_W[(n * D + d) * M + m];
  acc += X[idx];
  out[idx] = acc;
}

// ---------------------------------------------------------------------------
extern "C" void kernel_launch(void* const* d_in, const int* in_sizes, int n_in,
                              void* d_out, int out_size, void* d_ws, size_t ws_size,
                              hipStream_t stream) {
  const float* X     = (const float*)d_in[0];
  const float* pe    = (const float*)d_in[1];
  const float* E_W   = (const float*)d_in[2];
  const float* E_b   = (const float*)d_in[3];
  const float* tq_W  = (const float*)d_in[4];
  const float* tq_b  = (const float*)d_in[5];
  const float* tk_W  = (const float*)d_in[6];
  const float* tk_b  = (const float*)d_in[7];
  const float* tv_W  = (const float*)d_in[8];
  const float* tv_b  = (const float*)d_in[9];
  const float* tm_Wq = (const float*)d_in[10];
  const float* tm_bq = (const float*)d_in[11];
  const float* tm_Wk = (const float*)d_in[12];
  const float* tm_bk = (const float*)d_in[13];
  const float* tm_Wv = (const float*)d_in[14];
  const float* tm_bv = (const float*)d_in[15];
  const float* tm_Wo = (const float*)d_in[16];
  const float* tm_bo = (const float*)d_in[17];
  const float* sq_W  = (const float*)d_in[18];
  const float* sq_b  = (const float*)d_in[19];
  const float* sk_W  = (const float*)d_in[20];
  const float* sk_b  = (const float*)d_in[21];
  const float* sv_W  = (const float*)d_in[22];
  const float* sv_b  = (const float*)d_in[23];
  const float* sm_Wq = (const float*)d_in[24];
  const float* sm_bq = (const float*)d_in[25];
  const float* sm_Wk = (const float*)d_in[26];
  const float* sm_bk = (const float*)d_in[27];
  const float* sm_Wv = (const float*)d_in[28];
  const float* sm_bv = (const float*)d_in[29];
  const float* sm_Wo = (const float*)d_in[30];
  const float* sm_bo = (const float*)d_in[31];
  const float* ff1_W = (const float*)d_in[32];
  const float* ff1_b = (const float*)d_in[33];
  const float* ff2_W = (const float*)d_in[34];
  const float* ff2_b = (const float*)d_in[35];
  const float* ln_g  = (const float*)d_in[36];
  const float* ln_b  = (const float*)d_in[37];
  const float* op_W  = (const float*)d_in[38];
  const float* op_b  = (const float*)d_in[39];
  float* out = (float*)d_out;

  float* WtC = (float*)d_ws;                         // 3*N*D*D
  float* btC = WtC + 3 * N * D * D;                  // 3*N*D
  float* WsC = btC + 3 * N * D;                      // 3*T*D*D
  float* bsC = WsC + 3 * T * D * D;                  // 3*T*D
  size_t act = (size_t)B * T * N * D;
  bf16* Ebuf = (bf16*)(bsC + 3 * T * D);
  bf16* Tn   = Ebuf + act;
  bf16* Qt   = Tn + act;
  bf16* Kt   = Qt + act;
  bf16* Vt   = Kt + act;
  bf16* Sn   = Qt;                                   // alias

  compose3_kernel<<<3 * N, 256, 0, stream>>>(
      tq_W, tq_b, tm_Wq, tm_bq, tk_W, tk_b, tm_Wk, tm_bk,
      tv_W, tv_b, tm_Wv, tm_bv, WtC, btC, N);
  compose3_kernel<<<3 * T, 256, 0, stream>>>(
      sq_W, sq_b, sm_Wq, sm_bq, sk_W, sk_b, sm_Wk, sm_bk,
      sv_W, sv_b, sm_Wv, sm_bv, WsC, bsC, T);

  embed_kernel<<<(B * T * N * D) / 256, 256, 0, stream>>>(X, pe, E_W, E_b, Ebuf);

  for (int l = 0; l < L; ++l) {
    qkvt_kernel<<<N * QCH, 256, 0, stream>>>(Ebuf, WtC, btC, Qt, Kt, Vt);
    attnt_kernel<<<B * N * 4, 256, 0, stream>>>(Qt, Kt, Vt, Ebuf, tm_Wo, tm_bo, ln_g, ln_b, Tn);
    spatial_kernel<<<T * (B / BG), 256, 0, stream>>>(Ebuf, WsC, bsC, sm_Wo, sm_bo, ln_g, ln_b, Sn);
    ff_kernel<<<(B * T * N) / FR, 256, 0, stream>>>(Tn, Sn, ff1_W, ff1_b, ff2_W, ff2_b, ln_g, ln_b, Ebuf);
  }

  out_kernel<<<(B * T * N * M + 255) / 256, 256, 0, stream>>>(Ebuf, op_W, op_b, X, out);
}

// Round 20
// 793.875 us; speedup vs baseline: 1.3921x; 1.0402x over previous
//
#include <hip/hip_runtime.h>
#include <hip/hip_bf16.h>

typedef __hip_bfloat16 bf16;

constexpr int B  = 64, T = 120, N = 24, M = 3, D = 32;
constexpr int NH = 2, FD = 16, FF = 64, L = 3;
constexpr float SCALE = 0.25f;   // 1/sqrt(FD)
constexpr int SK  = 40;          // attnt Q/V LDS stride (bf16, 80B rows)
constexpr int SKF = 36;          // attnt K/O LDS stride (f32, 144B rows)
constexpr int CH2 = 30;          // attnt rows per chunk: 4 x 30 = 120 exactly
constexpr int NJ  = 30;          // max keys per lane slice (120/4)
constexpr int QR  = 64;          // qkvt rows per block (4 lanes/row)
constexpr int QCH = (B * T) / QR;// qkvt chunks = 120
constexpr int BG  = 2;           // spatial batches per block
constexpr int SR  = N * BG;      // spatial rows per block = 48
constexpr int SES = 40;          // Es bf16 stride (80B)
constexpr int SQS = 33;          // spatial Q/K/V f32 stride (no 32-way conflicts)
constexpr int FR  = 32;          // ff rows per block (8 lanes/row)

__device__ __forceinline__ float b2f(bf16 x) { return __bfloat162float(x); }
__device__ __forceinline__ float blo(unsigned u) { return __uint_as_float(u << 16); }
__device__ __forceinline__ float bhi(unsigned u) { return __uint_as_float(u & 0xffff0000u); }
__device__ __forceinline__ unsigned pk2(float a, float b) {
  bf16 x = __float2bfloat16(a), y = __float2bfloat16(b);
  unsigned short ux = *reinterpret_cast<unsigned short*>(&x);
  unsigned short uy = *reinterpret_cast<unsigned short*>(&y);
  return (unsigned)ux | ((unsigned)uy << 16);
}

// ---------------------------------------------------------------------------
// Compose q/k/v chained linears: grid = 3*U blocks.  Wc = W1@W2, bc = b1@W2+b2.
// ---------------------------------------------------------------------------
__global__ __launch_bounds__(256) void compose3_kernel(
    const float* __restrict__ W1q, const float* __restrict__ b1q,
    const float* __restrict__ W2q, const float* __restrict__ b2q,
    const float* __restrict__ W1k, const float* __restrict__ b1k,
    const float* __restrict__ W2k, const float* __restrict__ b2k,
    const float* __restrict__ W1v, const float* __restrict__ b1v,
    const float* __restrict__ W2v, const float* __restrict__ b2v,
    float* __restrict__ Wc, float* __restrict__ bc, int U) {
  int fam = blockIdx.x / U;
  int n   = blockIdx.x % U;
  const float* W1 = (fam == 0) ? W1q : (fam == 1) ? W1k : W1v;
  const float* b1 = (fam == 0) ? b1q : (fam == 1) ? b1k : b1v;
  const float* W2 = (fam == 0) ? W2q : (fam == 1) ? W2k : W2v;
  const float* b2 = (fam == 0) ? b2q : (fam == 1) ? b2k : b2v;
  const float* w1 = W1 + n * D * D;
  const float* w2 = W2 + n * D * D;
  float* wc  = Wc + (size_t)(fam * U + n) * D * D;
  float* bcp = bc + (fam * U + n) * D;
  __shared__ float s1[D * D], s2[D * D];
  for (int i = threadIdx.x; i < D * D; i += 256) { s1[i] = w1[i]; s2[i] = w2[i]; }
  __syncthreads();
  for (int i = threadIdx.x; i < D * D; i += 256) {
    int d = i >> 5, f = i & 31;
    float acc = 0.f;
#pragma unroll
    for (int e = 0; e < D; ++e) acc += s1[d * D + e] * s2[e * D + f];
    wc[i] = acc;
  }
  if (threadIdx.x < D) {
    int f = threadIdx.x;
    float acc = b2[n * D + f];
#pragma unroll
    for (int e = 0; e < D; ++e) acc += b1[n * D + e] * s2[e * D + f];
    bcp[f] = acc;
  }
}

// ---------------------------------------------------------------------------
// E[b,t,n,d] = X@E_W + E_b + pe   (bf16 out)
// ---------------------------------------------------------------------------
__global__ __launch_bounds__(256) void embed_kernel(
    const float* __restrict__ X, const float* __restrict__ pe,
    const float* __restrict__ E_W, const float* __restrict__ E_b,
    bf16* __restrict__ E) {
  int idx = blockIdx.x * 256 + threadIdx.x;
  if (idx >= B * T * N * D) return;
  int d = idx & 31;
  int n = (idx >> 5) % N;
  int bt = idx / (D * N);
  int t = bt % T;
  const float* x = X + bt * (N * M) + n * M;
  float acc = E_b[n * D + d] + pe[t * D + d];
#pragma unroll
  for (int m = 0; m < M; ++m) acc += x[m] * E_W[(n * M + m) * D + d];
  E[idx] = __float2bfloat16(acc);
}

// ---------------------------------------------------------------------------
// qkvt v2: thread = (row, quarter); LDS-staged coalesced loads, one
// contiguous uint4 store per family.  Grid n-major for weight L2 reuse.
// ---------------------------------------------------------------------------
__global__ __launch_bounds__(256) void qkvt_kernel(
    const bf16* __restrict__ E, const float* __restrict__ WtC,
    const float* __restrict__ btC,
    bf16* __restrict__ Qt, bf16* __restrict__ Kt, bf16* __restrict__ Vt) {
  int n     = blockIdx.x / QCH;
  int chunk = blockIdx.x % QCH;
  __shared__ float wsh[3 * D * D];
  __shared__ float bsh[3 * D];
  __shared__ __align__(16) bf16 Es[QR * SES];
  int tid = threadIdx.x;
  for (int i = tid; i < 3 * D * D; i += 256) {
    int fam = i >> 10, idx = i & 1023;
    wsh[i] = WtC[(size_t)(fam * N + n) * D * D + idx];
  }
  if (tid < 3 * D) {
    int fam = tid >> 5, e = tid & 31;
    bsh[tid] = btC[(fam * N + n) * D + e];
  }
  {
    int row = tid >> 2, p = tid & 3;
    const bf16* er = E + ((size_t)(chunk * QR + row) * N + n) * D;
    *(uint4*)&Es[row * SES + p * 8] = *(const uint4*)&er[p * 8];
  }
  __syncthreads();

  int row = tid >> 2, q = tid & 3;
  int grow = chunk * QR + row;          // b*T + t
  int b = grow / T, t = grow % T;
  float x[D];
#pragma unroll
  for (int d = 0; d < D; ++d) x[d] = b2f(Es[row * SES + d]);
  size_t dsto = (((size_t)b * N + n) * T + t) * D + q * 8;
  bf16* dsts[3] = { Qt + dsto, Kt + dsto, Vt + dsto };
#pragma unroll
  for (int fam = 0; fam < 3; ++fam) {
    const float* w  = wsh + fam * D * D;
    const float* bi = bsh + fam * D;
    float a[8];
#pragma unroll
    for (int j = 0; j < 8; ++j) a[j] = bi[q * 8 + j];
#pragma unroll
    for (int d = 0; d < D; ++d) {
      float xv = x[d];
#pragma unroll
      for (int j = 0; j < 8; ++j) a[j] += xv * w[d * D + q * 8 + j];
    }
    uint4 o;
    o.x = pk2(a[0], a[1]); o.y = pk2(a[2], a[3]);
    o.z = pk2(a[4], a[5]); o.w = pk2(a[6], a[7]);
    *(uint4*)dsts[fam] = o;
  }
}

// ---------------------------------------------------------------------------
// attnt v9: ONE block per (b,n); K/V staged ONCE (was 2.5x re-staged across
// the 4 chunk-blocks: FETCH 46.4MB vs ~31 ideal), chunks looped with
// {stage Ql; barrier; attention; barrier; O-proj}.  Barrier proof: next-iter
// Ql staging races only with O-proj (no reader); attention(c+1)'s Ol writes
// are fenced by the loop-head barrier reached after O-proj(c).  Uniform
// per-block work (kills the 4:1 c-imbalance).  Attention body = v4 verbatim.
// ---------------------------------------------------------------------------
__global__ __launch_bounds__(256) void attnt_kernel(
    const bf16* __restrict__ Qt, const bf16* __restrict__ Kt,
    const bf16* __restrict__ Vt, const bf16* __restrict__ E,
    const float* __restrict__ tm_Wo, const float* __restrict__ tm_bo,
    const float* __restrict__ ln_g, const float* __restrict__ ln_b,
    bf16* __restrict__ Tn) {
  int bn = blockIdx.x;
  int n  = bn % N, b = bn / N;
  __shared__ __align__(16) float Kl[T * SKF];
  __shared__ __align__(16) bf16  Vl[T * SK];
  __shared__ __align__(16) bf16  Ql[CH2 * SK];
  __shared__ __align__(16) float Ol[CH2 * SKF];
  __shared__ float Wol[D * D], bol[D], gl[D], bbl[D];
  int tid = threadIdx.x;

  const bf16* Kg = Kt + (size_t)bn * T * D;
  const bf16* Vg = Vt + (size_t)bn * T * D;
  const bf16* Qg = Qt + (size_t)bn * T * D;
  for (int i = tid; i < T * 4; i += 256) {
    int r = i >> 2, p = i & 3;
    uint4 ku = *(const uint4*)&Kg[r * D + p * 8];
    *(float4*)&Kl[r * SKF + p * 8]     = make_float4(blo(ku.x), bhi(ku.x), blo(ku.y), bhi(ku.y));
    *(float4*)&Kl[r * SKF + p * 8 + 4] = make_float4(blo(ku.z), bhi(ku.z), blo(ku.w), bhi(ku.w));
    *(uint4*)&Vl[r * SK + p * 8]       = *(const uint4*)&Vg[r * D + p * 8];
  }
  for (int i = tid; i < D * D; i += 256) Wol[i] = tm_Wo[(size_t)n * D * D + i];
  if (tid < D) {
    bol[tid] = tm_bo[n * D + tid];
    gl[tid]  = ln_g[tid];
    bbl[tid] = ln_b[tid];
  }
  __syncthreads();

#pragma unroll 1
  for (int c = 0; c < 4; ++c) {
    // stage this chunk's Q (30 rows); races only with prior O-proj (no reader)
    if (tid < CH2 * 4) {
      int r = tid >> 2, p = tid & 3;
      *(uint4*)&Ql[r * SK + p * 8] =
          *(const uint4*)&Qg[(CH2 * c + r) * D + p * 8];
    }
    __syncthreads();   // Ql ready; prior O-proj done -> Ol safe to overwrite

    // ---- attention: task = (row, head), 4 lanes per task ----
    {
      int task = tid >> 2, sl = tid & 3;
      if (task < 2 * CH2) {
        int rl = task >> 1, h = task & 1, ho = h * FD;
        int rg = CH2 * c + rl;
        uint4 q0 = *(const uint4*)&Ql[rl * SK + ho];
        uint4 q1 = *(const uint4*)&Ql[rl * SK + ho + 8];
        float qf[16];
        qf[0]  = blo(q0.x); qf[1]  = bhi(q0.x); qf[2]  = blo(q0.y); qf[3]  = bhi(q0.y);
        qf[4]  = blo(q0.z); qf[5]  = bhi(q0.z); qf[6]  = blo(q0.w); qf[7]  = bhi(q0.w);
        qf[8]  = blo(q1.x); qf[9]  = bhi(q1.x); qf[10] = blo(q1.y); qf[11] = bhi(q1.y);
        qf[12] = blo(q1.z); qf[13] = bhi(q1.z); qf[14] = blo(q1.w); qf[15] = bhi(q1.w);

        float sc[NJ];
        float mx = -3e38f;
#pragma unroll
        for (int j = 0; j < NJ; ++j) {
          int k = 4 * j + sl;
          sc[j] = -3e38f;
          if (k <= rg) {
            const float4 k0 = *(const float4*)&Kl[k * SKF + ho];
            const float4 k1 = *(const float4*)&Kl[k * SKF + ho + 4];
            const float4 k2 = *(const float4*)&Kl[k * SKF + ho + 8];
            const float4 k3 = *(const float4*)&Kl[k * SKF + ho + 12];
            float s0 = qf[0]*k0.x  + qf[1]*k0.y  + qf[2]*k0.z  + qf[3]*k0.w;
            float s1 = qf[4]*k1.x  + qf[5]*k1.y  + qf[6]*k1.z  + qf[7]*k1.w;
            float s2 = qf[8]*k2.x  + qf[9]*k2.y  + qf[10]*k2.z + qf[11]*k2.w;
            float s3 = qf[12]*k3.x + qf[13]*k3.y + qf[14]*k3.z + qf[15]*k3.w;
            float s = ((s0 + s1) + (s2 + s3)) * SCALE;
            sc[j] = s;
            mx = fmaxf(mx, s);
          }
        }
        mx = fmaxf(mx, __shfl_xor(mx, 1, 64));
        mx = fmaxf(mx, __shfl_xor(mx, 2, 64));
        float l = 0.f;
#pragma unroll
        for (int j = 0; j < NJ; ++j) {
          sc[j] = __expf(sc[j] - mx);   // invalid slots: exp(-inf) = 0
          l += sc[j];
        }
        l += __shfl_xor(l, 1, 64);
        l += __shfl_xor(l, 2, 64);
        float rli = 1.f / l;

        float acc[16];
#pragma unroll
        for (int f = 0; f < 16; ++f) acc[f] = 0.f;
#pragma unroll
        for (int j = 0; j < NJ; ++j) {
          int k = 4 * j + sl;
          if (k <= rg) {
            float p = sc[j];
            uint2 va = *(const uint2*)&Vl[k * SK + ho];
            uint2 vb = *(const uint2*)&Vl[k * SK + ho + 4];
            uint2 vc = *(const uint2*)&Vl[k * SK + ho + 8];
            uint2 vd = *(const uint2*)&Vl[k * SK + ho + 12];
            acc[0]  += p * blo(va.x); acc[1]  += p * bhi(va.x);
            acc[2]  += p * blo(va.y); acc[3]  += p * bhi(va.y);
            acc[4]  += p * blo(vb.x); acc[5]  += p * bhi(vb.x);
            acc[6]  += p * blo(vb.y); acc[7]  += p * bhi(vb.y);
            acc[8]  += p * blo(vc.x); acc[9]  += p * bhi(vc.x);
            acc[10] += p * blo(vc.y); acc[11] += p * bhi(vc.y);
            acc[12] += p * blo(vd.x); acc[13] += p * bhi(vd.x);
            acc[14] += p * blo(vd.y); acc[15] += p * bhi(vd.y);
          }
        }
#pragma unroll
        for (int f = 0; f < 16; ++f) {
          acc[f] += __shfl_xor(acc[f], 1, 64);
          acc[f] += __shfl_xor(acc[f], 2, 64);
        }
        if (sl == 0) {
#pragma unroll
          for (int f = 0; f < 16; ++f) Ol[rl * SKF + ho + f] = acc[f] * rli;
        }
      }
    }
    __syncthreads();

    // ---- O-proj + residual + LN: thread = (row, e-quad) ----
    {
      int rl = tid >> 3, q = tid & 7, e0 = q * 4;
      if (rl < CH2) {
        int rg = CH2 * c + rl;
        size_t rowo = ((size_t)(b * T + rg) * N + n) * D;
        uint2 eu = *(const uint2*)&E[rowo + e0];
        float res[4] = { blo(eu.x), bhi(eu.x), blo(eu.y), bhi(eu.y) };
        float o[4], s1 = 0.f, s2 = 0.f;
#pragma unroll
        for (int j = 0; j < 4; ++j) {
          int e = e0 + j;
          float aa = 0.f, ab = 0.f;
#pragma unroll
          for (int d = 0; d < D; d += 2) {
            aa += Ol[rl * SKF + d]     * Wol[d * D + e];
            ab += Ol[rl * SKF + d + 1] * Wol[(d + 1) * D + e];
          }
          float a = bol[e] + aa + ab + res[j];
          o[j] = a; s1 += a; s2 += a * a;
        }
        s1 += __shfl_xor(s1, 1, 64); s2 += __shfl_xor(s2, 1, 64);
        s1 += __shfl_xor(s1, 2, 64); s2 += __shfl_xor(s2, 2, 64);
        s1 += __shfl_xor(s1, 4, 64); s2 += __shfl_xor(s2, 4, 64);
        float mu  = s1 * (1.f / D);
        float var = s2 * (1.f / D) - mu * mu;
        float r = rsqrtf(var + 1e-5f);
        uint2 ou;
        ou.x = pk2((o[0]-mu)*r*gl[e0]+bbl[e0],    (o[1]-mu)*r*gl[e0+1]+bbl[e0+1]);
        ou.y = pk2((o[2]-mu)*r*gl[e0+2]+bbl[e0+2],(o[3]-mu)*r*gl[e0+3]+bbl[e0+3]);
        *(uint2*)&Tn[rowo + e0] = ou;
      }
    }
  }
}

// ---------------------------------------------------------------------------
// spatial v3: SQS=33 (stride-32 f32 rows were a 32-way bank conflict).
// ---------------------------------------------------------------------------
__global__ __launch_bounds__(256) void spatial_kernel(
    const bf16* __restrict__ E, const float* __restrict__ WsC,
    const float* __restrict__ bsC, const float* __restrict__ sm_Wo,
    const float* __restrict__ sm_bo, const float* __restrict__ ln_g,
    const float* __restrict__ ln_b, bf16* __restrict__ Sn) {
  int t  = blockIdx.x >> 5;          // B/BG = 32 groups per t
  int bg = blockIdx.x & 31;
  int b0 = bg * BG;
  __shared__ float Wq[D * D], Wk[D * D], Wv[D * D], Wo[D * D];
  __shared__ float bqs[D], bks[D], bvs[D], bos[D], gs[D], bbs[D];
  __shared__ __align__(16) bf16  Es[SR * SES];
  __shared__ float Qs[SR * SQS], Ks[SR * SQS], Vs[SR * SQS];
  int tid = threadIdx.x;

  for (int i = tid; i < D * D; i += 256) {
    Wq[i] = WsC[(size_t)(0 * T + t) * D * D + i];
    Wk[i] = WsC[(size_t)(1 * T + t) * D * D + i];
    Wv[i] = WsC[(size_t)(2 * T + t) * D * D + i];
    Wo[i] = sm_Wo[(size_t)t * D * D + i];
  }
  if (tid < D) {
    bqs[tid] = bsC[(0 * T + t) * D + tid];
    bks[tid] = bsC[(1 * T + t) * D + tid];
    bvs[tid] = bsC[(2 * T + t) * D + tid];
    bos[tid] = sm_bo[t * D + tid];
    gs[tid]  = ln_g[tid];
    bbs[tid] = ln_b[tid];
  }
  if (tid < SR * 4) {
    int r = tid >> 2, p = tid & 3;
    int b = b0 + r / N, n = r % N;
    *(uint4*)&Es[r * SES + p * 8] =
        *(const uint4*)&E[(((size_t)b * T + t) * N + n) * D + p * 8];
  }
  __syncthreads();

#pragma unroll 1
  for (int i = tid; i < SR * D; i += 256) {
    int r = i >> 5, e = i & 31;
    float aq = bqs[e], ak = bks[e], av = bvs[e];
#pragma unroll
    for (int d = 0; d < D; ++d) {
      float x = b2f(Es[r * SES + d]);
      aq += x * Wq[d * D + e];
      ak += x * Wk[d * D + e];
      av += x * Wv[d * D + e];
    }
    Qs[r * SQS + e] = aq;
    Ks[r * SQS + e] = ak;
    Vs[r * SQS + e] = av;
  }
  __syncthreads();

  if (tid < SR * NH) {
    int r = tid >> 1, h = tid & 1, ho = h * FD;
    int kb = (r >= N) ? N : 0;
    float q[FD];
#pragma unroll
    for (int f = 0; f < FD; ++f) q[f] = Qs[r * SQS + ho + f];
    float sc[N];
    float m = -1e30f;
#pragma unroll
    for (int k = 0; k < N; ++k) {
      float sa = 0.f, sb = 0.f;
#pragma unroll
      for (int f = 0; f < FD; f += 2) {
        sa += q[f]     * Ks[(kb + k) * SQS + ho + f];
        sb += q[f + 1] * Ks[(kb + k) * SQS + ho + f + 1];
      }
      float s = (sa + sb) * SCALE;
      sc[k] = s;
      m = fmaxf(m, s);
    }
    float l = 0.f;
#pragma unroll
    for (int k = 0; k < N; ++k) { sc[k] = __expf(sc[k] - m); l += sc[k]; }
    float rl = 1.f / l;
#pragma unroll
    for (int f = 0; f < FD; ++f) {
      float a = 0.f;
#pragma unroll
      for (int k = 0; k < N; ++k) a += sc[k] * Vs[(kb + k) * SQS + ho + f];
      Qs[r * SQS + ho + f] = a * rl;
    }
  }
  __syncthreads();

#pragma unroll 1
  for (int it = 0; it < SR * D / 256; ++it) {
    int i = it * 256 + tid;
    int r = i >> 5, e = i & 31;
    float aa = 0.f, ab = 0.f;
#pragma unroll
    for (int d = 0; d < D; d += 2) {
      aa += Qs[r * SQS + d]     * Wo[d * D + e];
      ab += Qs[r * SQS + d + 1] * Wo[(d + 1) * D + e];
    }
    float o = bos[e] + aa + ab + b2f(Es[r * SES + e]);
    float s1 = o, s2 = o * o;
    s1 += __shfl_xor(s1, 1, 64);  s2 += __shfl_xor(s2, 1, 64);
    s1 += __shfl_xor(s1, 2, 64);  s2 += __shfl_xor(s2, 2, 64);
    s1 += __shfl_xor(s1, 4, 64);  s2 += __shfl_xor(s2, 4, 64);
    s1 += __shfl_xor(s1, 8, 64);  s2 += __shfl_xor(s2, 8, 64);
    s1 += __shfl_xor(s1, 16, 64); s2 += __shfl_xor(s2, 16, 64);
    float mu  = s1 * (1.f / D);
    float var = s2 * (1.f / D) - mu * mu;
    float rr = rsqrtf(var + 1e-5f);
    int b = b0 + r / N, n = r % N;
    Sn[(((size_t)b * T + t) * N + n) * D + e] =
        __float2bfloat16((o - mu) * rr * gs[e] + bbs[e]);
  }
}

// ---------------------------------------------------------------------------
// ff v2: block = 32 rows x 8 lanes/row (grid 240).
// ---------------------------------------------------------------------------
__global__ __launch_bounds__(256) void ff_kernel(
    const bf16* __restrict__ Tn, const bf16* __restrict__ Sn,
    const float* __restrict__ W1, const float* __restrict__ b1,
    const float* __restrict__ W2, const float* __restrict__ b2,
    const float* __restrict__ ln_g, const float* __restrict__ ln_b,
    bf16* __restrict__ E) {
  __shared__ float w1s[D * FF], w2s[FF * D];
  __shared__ float bb1[FF], bb2[D], gs[D], bbs[D];
  __shared__ float tsl[FR][D + 1];
  __shared__ float hl[FR][FF + 1];
  int tid = threadIdx.x;
  int r0 = blockIdx.x * FR;
  for (int i = tid; i < D * FF; i += 256) { w1s[i] = W1[i]; w2s[i] = W2[i]; }
  if (tid < FF) bb1[tid] = b1[tid];
  if (tid < D) { bb2[tid] = b2[tid]; gs[tid] = ln_g[tid]; bbs[tid] = ln_b[tid]; }
  int r = tid >> 3, s = tid & 7;
  {
    const bf16* tp = Tn + ((size_t)(r0 + r)) * D + s * 4;
    const bf16* sp = Sn + ((size_t)(r0 + r)) * D + s * 4;
    uint2 tu = *(const uint2*)tp;
    uint2 su = *(const uint2*)sp;
    tsl[r][s*4+0] = blo(tu.x) + blo(su.x);
    tsl[r][s*4+1] = bhi(tu.x) + bhi(su.x);
    tsl[r][s*4+2] = blo(tu.y) + blo(su.y);
    tsl[r][s*4+3] = bhi(tu.y) + bhi(su.y);
  }
  __syncthreads();
  {
    float hh[8];
#pragma unroll
    for (int j = 0; j < 8; ++j) {
      int jj = s * 8 + j;
      float aa = bb1[jj], ab = 0.f;
#pragma unroll
      for (int d = 0; d < D; d += 2) {
        aa += tsl[r][d]     * w1s[d * FF + jj];
        ab += tsl[r][d + 1] * w1s[(d + 1) * FF + jj];
      }
      hh[j] = fmaxf(aa + ab, 0.f);
    }
#pragma unroll
    for (int j = 0; j < 8; ++j) hl[r][s * 8 + j] = hh[j];
  }
  __syncthreads();
  {
    float x[4];
    float s1 = 0.f, s2 = 0.f;
#pragma unroll
    for (int j4 = 0; j4 < 4; ++j4) {
      int e = s * 4 + j4;
      float aa = 0.f, ab = 0.f;
#pragma unroll
      for (int k = 0; k < FF; k += 2) {
        aa += hl[r][k]     * w2s[k * D + e];
        ab += hl[r][k + 1] * w2s[(k + 1) * D + e];
      }
      float a = bb2[e] + tsl[r][e] + aa + ab;
      x[j4] = a; s1 += a; s2 += a * a;
    }
    s1 += __shfl_xor(s1, 1, 64); s2 += __shfl_xor(s2, 1, 64);
    s1 += __shfl_xor(s1, 2, 64); s2 += __shfl_xor(s2, 2, 64);
    s1 += __shfl_xor(s1, 4, 64); s2 += __shfl_xor(s2, 4, 64);
    float mu  = s1 * (1.f / D);
    float var = s2 * (1.f / D) - mu * mu;
    float rr = rsqrtf(var + 1e-5f);
    int e0 = s * 4;
    uint2 ou;
    ou.x = pk2((x[0]-mu)*rr*gs[e0]+bbs[e0],    (x[1]-mu)*rr*gs[e0+1]+bbs[e0+1]);
    ou.y = pk2((x[2]-mu)*rr*gs[e0+2]+bbs[e0+2],(x[3]-mu)*rr*gs[e0+3]+bbs[e0+3]);
    *(uint2*)&E[((size_t)(r0 + r)) * D + e0] = ou;
  }
}

// ---------------------------------------------------------------------------
// out = E@op_W + op_b + X   (f32 out)
// ---------------------------------------------------------------------------
__global__ __launch_bounds__(256) void out_kernel(
    const bf16* __restrict__ E, const float* __restrict__ op_W,
    const float* __restrict__ op_b, const float* __restrict__ X,
    float* __restrict__ out) {
  int idx = blockIdx.x * 256 + threadIdx.x;
  if (idx >= B * T * N * M) return;
  int m  = idx % M;
  int n  = (idx / M) % N;
  int bt = idx / (M * N);
  float acc = op_b[n * M + m];
  const bf16* e = E + ((size_t)bt * N + n) * D;
#pragma unroll
  for (int d = 0; d < D; ++d) acc += b2f(e[d]) * op_W[(n * D + d) * M + m];
  acc += X[idx];
  out[idx] = acc;
}

// ---------------------------------------------------------------------------
extern "C" void kernel_launch(void* const* d_in, const int* in_sizes, int n_in,
                              void* d_out, int out_size, void* d_ws, size_t ws_size,
                              hipStream_t stream) {
  const float* X     = (const float*)d_in[0];
  const float* pe    = (const float*)d_in[1];
  const float* E_W   = (const float*)d_in[2];
  const float* E_b   = (const float*)d_in[3];
  const float* tq_W  = (const float*)d_in[4];
  const float* tq_b  = (const float*)d_in[5];
  const float* tk_W  = (const float*)d_in[6];
  const float* tk_b  = (const float*)d_in[7];
  const float* tv_W  = (const float*)d_in[8];
  const float* tv_b  = (const float*)d_in[9];
  const float* tm_Wq = (const float*)d_in[10];
  const float* tm_bq = (const float*)d_in[11];
  const float* tm_Wk = (const float*)d_in[12];
  const float* tm_bk = (const float*)d_in[13];
  const float* tm_Wv = (const float*)d_in[14];
  const float* tm_bv = (const float*)d_in[15];
  const float* tm_Wo = (const float*)d_in[16];
  const float* tm_bo = (const float*)d_in[17];
  const float* sq_W  = (const float*)d_in[18];
  const float* sq_b  = (const float*)d_in[19];
  const float* sk_W  = (const float*)d_in[20];
  const float* sk_b  = (const float*)d_in[21];
  const float* sv_W  = (const float*)d_in[22];
  const float* sv_b  = (const float*)d_in[23];
  const float* sm_Wq = (const float*)d_in[24];
  const float* sm_bq = (const float*)d_in[25];
  const float* sm_Wk = (const float*)d_in[26];
  const float* sm_bk = (const float*)d_in[27];
  const float* sm_Wv = (const float*)d_in[28];
  const float* sm_bv = (const float*)d_in[29];
  const float* sm_Wo = (const float*)d_in[30];
  const float* sm_bo = (const float*)d_in[31];
  const float* ff1_W = (const float*)d_in[32];
  const float* ff1_b = (const float*)d_in[33];
  const float* ff2_W = (const float*)d_in[34];
  const float* ff2_b = (const float*)d_in[35];
  const float* ln_g  = (const float*)d_in[36];
  const float* ln_b  = (const float*)d_in[37];
  const float* op_W  = (const float*)d_in[38];
  const float* op_b  = (const float*)d_in[39];
  float* out = (float*)d_out;

  float* WtC = (float*)d_ws;                         // 3*N*D*D
  float* btC = WtC + 3 * N * D * D;                  // 3*N*D
  float* WsC = btC + 3 * N * D;                      // 3*T*D*D
  float* bsC = WsC + 3 * T * D * D;                  // 3*T*D
  size_t act = (size_t)B * T * N * D;
  bf16* Ebuf = (bf16*)(bsC + 3 * T * D);
  bf16* Tn   = Ebuf + act;
  bf16* Qt   = Tn + act;
  bf16* Kt   = Qt + act;
  bf16* Vt   = Kt + act;
  bf16* Sn   = Qt;                                   // alias

  compose3_kernel<<<3 * N, 256, 0, stream>>>(
      tq_W, tq_b, tm_Wq, tm_bq, tk_W, tk_b, tm_Wk, tm_bk,
      tv_W, tv_b, tm_Wv, tm_bv, WtC, btC, N);
  compose3_kernel<<<3 * T, 256, 0, stream>>>(
      sq_W, sq_b, sm_Wq, sm_bq, sk_W, sk_b, sm_Wk, sm_bk,
      sv_W, sv_b, sm_Wv, sm_bv, WsC, bsC, T);

  embed_kernel<<<(B * T * N * D) / 256, 256, 0, stream>>>(X, pe, E_W, E_b, Ebuf);

  for (int l = 0; l < L; ++l) {
    qkvt_kernel<<<N * QCH, 256, 0, stream>>>(Ebuf, WtC, btC, Qt, Kt, Vt);
    attnt_kernel<<<B * N, 256, 0, stream>>>(Qt, Kt, Vt, Ebuf, tm_Wo, tm_bo, ln_g, ln_b, Tn);
    spatial_kernel<<<T * (B / BG), 256, 0, stream>>>(Ebuf, WsC, bsC, sm_Wo, sm_bo, ln_g, ln_b, Sn);
    ff_kernel<<<(B * T * N) / FR, 256, 0, stream>>>(Tn, Sn, ff1_W, ff1_b, ff2_W, ff2_b, ln_g, ln_b, Ebuf);
  }

  out_kernel<<<(B * T * N * M + 255) / 256, 256, 0, stream>>>(Ebuf, op_W, op_b, X, out);
}